// Round 4
// baseline (635.560 us; speedup 1.0000x reference)
//
#include <hip/hip_runtime.h>
#include <hip/hip_bf16.h>
#include <cstdint>
#include <cstddef>

#define NN 50000
#define NE 800000
#define INC 128
#define HIDC 256
#define NH 4
#define OUTC 40
#define MB 64
#define KT 32

__device__ __forceinline__ float lrelu(float x){ return x > 0.f ? x : 0.2f*x; }
__device__ __forceinline__ unsigned short bfr(float f){
  __hip_bfloat16 h = __float2bfloat16(f);
  return *reinterpret_cast<unsigned short*>(&h);
}

// ---- edge dtype detection: int64 view of int32 pairs gives values >= 2^32 ----
__global__ __launch_bounds__(64) void k_detect(const long long* __restrict__ ei, int* __restrict__ flag){
  int t = threadIdx.x;
  long long v = ei[(long long)t * (NE/64)];
  bool ok = (v >= 0) && (v < NN);
  unsigned long long m = __ballot(ok);
  if (t == 0) *flag = (m == 0xFFFFFFFFFFFFFFFFull) ? 1 : 0;
}

__global__ __launch_bounds__(256) void k_convert(const void* __restrict__ ei, const int* __restrict__ flag,
                                                 int* __restrict__ src32, int* __restrict__ dst32){
  int e = blockIdx.x*256 + threadIdx.x;
  if (e >= NE) return;
  int s, d;
  if (*flag){
    const long long* p = (const long long*)ei;
    s = (int)p[e]; d = (int)p[NE+e];
  } else {
    const int* p = (const int*)ei;
    s = p[e]; d = p[NE+e];
  }
  s = min(max(s,0),NN-1); d = min(max(d,0),NN-1);
  src32[e] = s; dst32[e] = d;
}

__global__ __launch_bounds__(256) void k_count(const int* __restrict__ dst32, int* __restrict__ deg){
  int e = blockIdx.x*256 + threadIdx.x;
  if (e < NE) atomicAdd(&deg[dst32[e]], 1);
}

// ---- exclusive scan of deg -> rowptr (3-kernel, chunk=1024) ----
__global__ __launch_bounds__(1024) void k_scan1(const int* __restrict__ deg, int* __restrict__ rowptr, int* __restrict__ sums){
  __shared__ int sh[1024];
  int t = threadIdx.x; int i = blockIdx.x*1024 + t;
  sh[t] = (i < NN) ? deg[i] : 0;
  __syncthreads();
  for (int off = 1; off < 1024; off <<= 1){
    int add = (t >= off) ? sh[t-off] : 0;
    __syncthreads();
    sh[t] += add;
    __syncthreads();
  }
  if (i < NN) rowptr[i+1] = sh[t];
  if (t == 1023) sums[blockIdx.x] = sh[1023];
}

__global__ void k_scan2(int* sums, int nchunks){
  if (threadIdx.x == 0 && blockIdx.x == 0){
    int acc = 0;
    for (int i = 0; i < nchunks; i++){ int v = sums[i]; sums[i] = acc; acc += v; }
  }
}

__global__ __launch_bounds__(256) void k_scan3(int* __restrict__ rowptr, const int* __restrict__ sums){
  int i = blockIdx.x*256 + threadIdx.x;
  if (i < NN) rowptr[i+1] += sums[i >> 10];
  if (i == 0) rowptr[0] = 0;
}

__global__ __launch_bounds__(256) void k_fill(const int* __restrict__ src32, const int* __restrict__ dst32,
                                              const int* __restrict__ rowptr, int* __restrict__ fill,
                                              int* __restrict__ colsrc, int* __restrict__ epos){
  int e = blockIdx.x*256 + threadIdx.x;
  if (e >= NE) return;
  int d = dst32[e];
  int pos = rowptr[d] + atomicAdd(&fill[d], 1);
  colsrc[pos] = src32[e];
  epos[e] = pos;
}

// ---- layer1 GEMM v2: register-tiled fp32. Block = 64 nodes x 256 cols,
//      thread = 8x8 tile. A broadcast reads, B swizzled (4-way max). ----
__global__ __launch_bounds__(256) void k_gemm1(const float* __restrict__ x, const float* __restrict__ W1,
    const float* __restrict__ atts, const float* __restrict__ attd,
    __hip_bfloat16* __restrict__ h1b, float* __restrict__ as1, float* __restrict__ ad1){
  __shared__ float xs[MB*KT];        // [m][k] 8 KB
  __shared__ float ws[HIDC*KT];      // [c][k] 32 KB, float4-swizzled
  float4* xs4 = (float4*)xs;
  float4* ws4 = (float4*)ws;
  int tid = threadIdx.x;
  int tn = tid & 31, tm = tid >> 5;
  int n0 = blockIdx.x*MB;

  float acc[8][8];
  #pragma unroll
  for (int i = 0; i < 8; i++)
    #pragma unroll
    for (int j = 0; j < 8; j++) acc[i][j] = 0.f;

  for (int kc = 0; kc < INC/KT; kc++){
    // stage xs: 64 rows x 8 float4
    #pragma unroll
    for (int it = 0; it < 2; it++){
      int idx = it*256 + tid;
      int m = idx >> 3, kq = idx & 7;
      int gm = n0 + m;
      float4 v = make_float4(0.f,0.f,0.f,0.f);
      if (gm < NN) v = ((const float4*)(x + (size_t)gm*INC))[kc*8 + kq];
      xs4[m*8 + kq] = v;
    }
    // stage ws: 256 rows x 8 float4, swizzle granule: kq ^ ((c>>3)&7)
    #pragma unroll
    for (int it = 0; it < 8; it++){
      int idx = it*256 + tid;
      int c = idx >> 3, kq = idx & 7;
      ws4[c*8 + (kq ^ ((c>>3)&7))] = ((const float4*)(W1 + (size_t)c*INC))[kc*8 + kq];
    }
    __syncthreads();

    #pragma unroll
    for (int kq = 0; kq < 8; kq++){
      float4 a[8], b[8];
      #pragma unroll
      for (int i = 0; i < 8; i++) a[i] = xs4[(tm*8+i)*8 + kq];
      #pragma unroll
      for (int j = 0; j < 8; j++) b[j] = ws4[(tn*8+j)*8 + (kq ^ (tn & 7))];
      #pragma unroll
      for (int i = 0; i < 8; i++)
        #pragma unroll
        for (int j = 0; j < 8; j++)
          acc[i][j] += a[i].x*b[j].x + a[i].y*b[j].y + a[i].z*b[j].z + a[i].w*b[j].w;
    }
    __syncthreads();
  }

  // epilogue: bf16 store + attention dots (reduce over 8 lanes sharing a head)
  int c0 = tn*8;
  int head = tn >> 3;
  float attS[8], attD[8];
  #pragma unroll
  for (int j = 0; j < 8; j++){ attS[j] = atts[c0+j]; attD[j] = attd[c0+j]; }

  #pragma unroll
  for (int i = 0; i < 8; i++){
    int node = n0 + tm*8 + i;
    float ps = 0.f, pd = 0.f;
    unsigned u[4];
    #pragma unroll
    for (int j4 = 0; j4 < 4; j4++){
      float v0 = acc[i][j4*2+0], v1 = acc[i][j4*2+1];
      ps += v0*attS[j4*2] + v1*attS[j4*2+1];
      pd += v0*attD[j4*2] + v1*attD[j4*2+1];
      u[j4] = (unsigned)bfr(v0) | ((unsigned)bfr(v1) << 16);
    }
    #pragma unroll
    for (int off = 1; off < 8; off <<= 1){
      ps += __shfl_xor(ps, off);
      pd += __shfl_xor(pd, off);
    }
    if (node < NN){
      uint2* dst = (uint2*)((unsigned short*)h1b + (size_t)node*HIDC + c0);
      dst[0] = make_uint2(u[0], u[1]);
      dst[1] = make_uint2(u[2], u[3]);
      if ((tn & 7) == 0){ as1[node*NH + head] = ps; ad1[node*NH + head] = pd; }
    }
  }
}

// ---- per-edge attention weights for layer1 ----
__global__ __launch_bounds__(256) void k_es(const int* __restrict__ src32, const int* __restrict__ dst32,
    const int* __restrict__ epos, const float* __restrict__ as1, const float* __restrict__ ad1,
    float4* __restrict__ es4){
  int e = blockIdx.x*256 + threadIdx.x;
  if (e >= NE) return;
  int s = src32[e], d = dst32[e];
  float4 vs = ((const float4*)as1)[s];
  float4 vd = ((const float4*)ad1)[d];
  float4 r;
  r.x = __expf(lrelu(vs.x + vd.x));
  r.y = __expf(lrelu(vs.y + vd.y));
  r.z = __expf(lrelu(vs.z + vd.z));
  r.w = __expf(lrelu(vs.w + vd.w));
  es4[epos[e]] = r;
}

// ---- layer1 aggregation: bf16 gather, precomputed es, 2 ch/thread, unroll-2 ----
__global__ __launch_bounds__(128) void k_agg1(const __hip_bfloat16* __restrict__ h1b,
    const float4* __restrict__ es4, const float* __restrict__ as1, const float* __restrict__ ad1,
    const int* __restrict__ rowptr, const int* __restrict__ colsrc,
    const float* __restrict__ b1, float* __restrict__ h1a){
  int n = blockIdx.x; int tid = threadIdx.x; int head = tid >> 5;
  const unsigned* h1u = (const unsigned*)h1b;

  float es_self = __expf(lrelu(as1[n*NH + head] + ad1[n*NH + head]));
  float den = 1e-16f + es_self;
  unsigned v = h1u[(size_t)n*(HIDC/2) + tid];
  float a0 = es_self * __uint_as_float(v << 16);
  float a1 = es_self * __uint_as_float(v & 0xffff0000u);

  int beg = rowptr[n], end = rowptr[n+1];
  int j = beg;
  for (; j + 1 < end; j += 2){
    int s0 = colsrc[j], s1 = colsrc[j+1];
    float4 e0 = es4[j], e1 = es4[j+1];
    unsigned v0 = h1u[(size_t)s0*(HIDC/2) + tid];
    unsigned v1 = h1u[(size_t)s1*(HIDC/2) + tid];
    float w0 = (head & 2) ? ((head & 1) ? e0.w : e0.z) : ((head & 1) ? e0.y : e0.x);
    float w1 = (head & 2) ? ((head & 1) ? e1.w : e1.z) : ((head & 1) ? e1.y : e1.x);
    den += w0 + w1;
    a0 += w0 * __uint_as_float(v0 << 16);
    a1 += w0 * __uint_as_float(v0 & 0xffff0000u);
    a0 += w1 * __uint_as_float(v1 << 16);
    a1 += w1 * __uint_as_float(v1 & 0xffff0000u);
  }
  if (j < end){
    int s0 = colsrc[j];
    float4 e0 = es4[j];
    unsigned v0 = h1u[(size_t)s0*(HIDC/2) + tid];
    float w0 = (head & 2) ? ((head & 1) ? e0.w : e0.z) : ((head & 1) ? e0.y : e0.x);
    den += w0;
    a0 += w0 * __uint_as_float(v0 << 16);
    a1 += w0 * __uint_as_float(v0 & 0xffff0000u);
  }

  float2 bb = ((const float2*)b1)[tid];
  float rinv = 1.f / den;
  float o0 = a0*rinv + bb.x;
  float o1 = a1*rinv + bb.y;
  o0 = o0 > 0.f ? o0 : (__expf(o0) - 1.f);
  o1 = o1 > 0.f ? o1 : (__expf(o1) - 1.f);
  ((float2*)(h1a + (size_t)n*HIDC))[tid] = make_float2(o0, o1);
}

// ---- layer2 GEMM: one node per thread, W2^T staged in LDS ----
__global__ __launch_bounds__(256) void k_gemm2(const float* __restrict__ h1a, const float* __restrict__ W2,
    const float* __restrict__ atts2, const float* __restrict__ attd2,
    float* __restrict__ h2, float* __restrict__ a2s, float* __restrict__ a2d){
  __shared__ float W2t[HIDC*OUTC];   // [k][c] transposed, 40 KB
  __shared__ float sA[OUTC], sD[OUTC];
  int tid = threadIdx.x;
  #pragma unroll
  for (int it = 0; it < (OUTC*HIDC)/256; it++){
    int idx = it*256 + tid;
    int c = idx >> 8, k = idx & 255;
    W2t[k*OUTC + c] = W2[idx];
  }
  if (tid < OUTC){ sA[tid] = atts2[tid]; sD[tid] = attd2[tid]; }
  __syncthreads();

  int n = blockIdx.x*256 + tid;
  if (n >= NN) return;

  float acc[OUTC];
  #pragma unroll
  for (int c = 0; c < OUTC; c++) acc[c] = 0.f;

  const float4* x4p = (const float4*)(h1a + (size_t)n*HIDC);
  const float4* w4p = (const float4*)W2t;
  #pragma unroll 2
  for (int k4 = 0; k4 < HIDC/4; k4++){
    float4 xv = x4p[k4];
    #pragma unroll
    for (int kk = 0; kk < 4; kk++){
      float xk = (kk==0) ? xv.x : (kk==1) ? xv.y : (kk==2) ? xv.z : xv.w;
      #pragma unroll
      for (int c4 = 0; c4 < OUTC/4; c4++){
        float4 wv = w4p[(k4*4 + kk)*(OUTC/4) + c4];
        acc[c4*4+0] += xk*wv.x;
        acc[c4*4+1] += xk*wv.y;
        acc[c4*4+2] += xk*wv.z;
        acc[c4*4+3] += xk*wv.w;
      }
    }
  }

  float s2 = 0.f, d2 = 0.f;
  #pragma unroll
  for (int c = 0; c < OUTC; c++){ s2 += acc[c]*sA[c]; d2 += acc[c]*sD[c]; }

  float* h2row = h2 + (size_t)n*OUTC;
  #pragma unroll
  for (int c4 = 0; c4 < OUTC/4; c4++){
    float4 v; v.x = acc[c4*4+0]; v.y = acc[c4*4+1]; v.z = acc[c4*4+2]; v.w = acc[c4*4+3];
    ((float4*)h2row)[c4] = v;
  }
  a2s[n] = s2; a2d[n] = d2;
}

// ---- layer2 aggregation: softmax-weighted mean + bias -> out ----
__global__ __launch_bounds__(64) void k_agg2(const float* __restrict__ h2, const float* __restrict__ a2s,
    const float* __restrict__ a2d, const int* __restrict__ rowptr, const int* __restrict__ colsrc,
    const float* __restrict__ b2, float* __restrict__ out){
  int n = blockIdx.x; int tid = threadIdx.x;
  float adn = a2d[n];
  float e = __expf(lrelu(a2s[n] + adn));
  float den = 1e-16f + e;
  float acc = (tid < OUTC) ? e * h2[(size_t)n*OUTC + tid] : 0.f;
  int beg = rowptr[n], end = rowptr[n+1];
  for (int j = beg; j < end; j++){
    int s = colsrc[j];
    float es = __expf(lrelu(a2s[s] + adn));
    if (tid < OUTC) acc += es * h2[(size_t)s*OUTC + tid];
    den += es;
  }
  if (tid < OUTC) out[(size_t)n*OUTC + tid] = acc/den + b2[tid];
}

extern "C" void kernel_launch(void* const* d_in, const int* in_sizes, int n_in,
                              void* d_out, int out_size, void* d_ws, size_t ws_size,
                              hipStream_t stream){
  const float* x    = (const float*)d_in[0];
  const void*  ei   = d_in[1];
  const float* W1   = (const float*)d_in[2];
  const float* as1w = (const float*)d_in[3];
  const float* ad1w = (const float*)d_in[4];
  const float* b1   = (const float*)d_in[5];
  const float* W2   = (const float*)d_in[6];
  const float* as2w = (const float*)d_in[7];
  const float* ad2w = (const float*)d_in[8];
  const float* b2   = (const float*)d_in[9];
  float* out = (float*)d_out;

  char* base = (char*)d_ws;
  size_t off = 0;
  auto alloc = [&](size_t bytes)->char*{ char* r = base + off; off += (bytes + 255) & ~(size_t)255; return r; };
  int* flag   = (int*)alloc(sizeof(int));
  int* src32  = (int*)alloc((size_t)NE*sizeof(int));
  int* dst32  = (int*)alloc((size_t)NE*sizeof(int));
  int* deg    = (int*)alloc((size_t)NN*sizeof(int));
  int* rowptr = (int*)alloc((size_t)(NN+1)*sizeof(int));
  int* fillc  = (int*)alloc((size_t)NN*sizeof(int));
  int* sums   = (int*)alloc(64*sizeof(int));
  int* colsrc = (int*)alloc((size_t)NE*sizeof(int));
  int* epos   = (int*)alloc((size_t)NE*sizeof(int));
  float4* es4 = (float4*)alloc((size_t)NE*sizeof(float4));
  __hip_bfloat16* h1b = (__hip_bfloat16*)alloc((size_t)NN*HIDC*sizeof(__hip_bfloat16));
  float* h1a  = (float*)alloc((size_t)NN*HIDC*sizeof(float));
  float* as1  = (float*)alloc((size_t)NN*NH*sizeof(float));
  float* ad1  = (float*)alloc((size_t)NN*NH*sizeof(float));
  float* h2   = (float*)alloc((size_t)NN*OUTC*sizeof(float));
  float* a2s  = (float*)alloc((size_t)NN*sizeof(float));
  float* a2d  = (float*)alloc((size_t)NN*sizeof(float));

  hipMemsetAsync(deg,   0, (size_t)NN*sizeof(int), stream);
  hipMemsetAsync(fillc, 0, (size_t)NN*sizeof(int), stream);

  int gE = (NE + 255)/256;
  int nchunks = (NN + 1023)/1024;
  k_detect<<<1, 64, 0, stream>>>((const long long*)ei, flag);
  k_convert<<<gE, 256, 0, stream>>>(ei, flag, src32, dst32);
  k_count<<<gE, 256, 0, stream>>>(dst32, deg);
  k_scan1<<<nchunks, 1024, 0, stream>>>(deg, rowptr, sums);
  k_scan2<<<1, 64, 0, stream>>>(sums, nchunks);
  k_scan3<<<(NN + 255)/256, 256, 0, stream>>>(rowptr, sums);
  k_fill<<<gE, 256, 0, stream>>>(src32, dst32, rowptr, fillc, colsrc, epos);
  k_gemm1<<<(NN + MB - 1)/MB, 256, 0, stream>>>(x, W1, as1w, ad1w, h1b, as1, ad1);
  k_es<<<gE, 256, 0, stream>>>(src32, dst32, epos, as1, ad1, es4);
  k_agg1<<<NN, 128, 0, stream>>>(h1b, es4, as1, ad1, rowptr, colsrc, b1, h1a);
  k_gemm2<<<(NN + 255)/256, 256, 0, stream>>>(h1a, W2, as2w, ad2w, h2, a2s, a2d);
  k_agg2<<<NN, 64, 0, stream>>>(h2, a2s, a2d, rowptr, colsrc, b2, out);
}

// Round 5
// 402.058 us; speedup vs baseline: 1.5808x; 1.5808x over previous
//
#include <hip/hip_runtime.h>
#include <hip/hip_bf16.h>
#include <cstdint>
#include <cstddef>

#define NN 50000
#define NE 800000
#define INC 128
#define HIDC 256
#define NH 4
#define OUTC 40

__device__ __forceinline__ float lrelu(float x){ return x > 0.f ? x : 0.2f*x; }

// ---- edge dtype detection: int64 view of int32 pairs gives values >= 2^32 ----
__global__ __launch_bounds__(64) void k_detect(const long long* __restrict__ ei, int* __restrict__ flag){
  int t = threadIdx.x;
  long long v = ei[(long long)t * (NE/64)];
  bool ok = (v >= 0) && (v < NN);
  unsigned long long m = __ballot(ok);
  if (t == 0) *flag = (m == 0xFFFFFFFFFFFFFFFFull) ? 1 : 0;
}

__global__ __launch_bounds__(256) void k_convert(const void* __restrict__ ei, const int* __restrict__ flag,
                                                 int* __restrict__ src32, int* __restrict__ dst32){
  int e = blockIdx.x*256 + threadIdx.x;
  if (e >= NE) return;
  int s, d;
  if (*flag){
    const long long* p = (const long long*)ei;
    s = (int)p[e]; d = (int)p[NE+e];
  } else {
    const int* p = (const int*)ei;
    s = p[e]; d = p[NE+e];
  }
  s = min(max(s,0),NN-1); d = min(max(d,0),NN-1);
  src32[e] = s; dst32[e] = d;
}

__global__ __launch_bounds__(256) void k_count(const int* __restrict__ dst32, int* __restrict__ deg){
  int e = blockIdx.x*256 + threadIdx.x;
  if (e < NE) atomicAdd(&deg[dst32[e]], 1);
}

// ---- exclusive scan of deg -> rowptr (3-kernel, chunk=1024) ----
__global__ __launch_bounds__(1024) void k_scan1(const int* __restrict__ deg, int* __restrict__ rowptr, int* __restrict__ sums){
  __shared__ int sh[1024];
  int t = threadIdx.x; int i = blockIdx.x*1024 + t;
  sh[t] = (i < NN) ? deg[i] : 0;
  __syncthreads();
  for (int off = 1; off < 1024; off <<= 1){
    int add = (t >= off) ? sh[t-off] : 0;
    __syncthreads();
    sh[t] += add;
    __syncthreads();
  }
  if (i < NN) rowptr[i+1] = sh[t];
  if (t == 1023) sums[blockIdx.x] = sh[1023];
}

__global__ void k_scan2(int* sums, int nchunks){
  if (threadIdx.x == 0 && blockIdx.x == 0){
    int acc = 0;
    for (int i = 0; i < nchunks; i++){ int v = sums[i]; sums[i] = acc; acc += v; }
  }
}

__global__ __launch_bounds__(256) void k_scan3(int* __restrict__ rowptr, const int* __restrict__ sums){
  int i = blockIdx.x*256 + threadIdx.x;
  if (i < NN) rowptr[i+1] += sums[i >> 10];
  if (i == 0) rowptr[0] = 0;
}

__global__ __launch_bounds__(256) void k_fill(const int* __restrict__ src32, const int* __restrict__ dst32,
                                              const int* __restrict__ rowptr, int* __restrict__ fill,
                                              int* __restrict__ colsrc, int* __restrict__ epos){
  int e = blockIdx.x*256 + threadIdx.x;
  if (e >= NE) return;
  int d = dst32[e];
  int pos = rowptr[d] + atomicAdd(&fill[d], 1);
  colsrc[pos] = src32[e];
  epos[e] = pos;
}

// ---- layer1 GEMM v3: no LDS. x read via wave-uniform address -> s_load (scalar pipe);
//      W per-thread from L2. 8 nodes/block, thread=col. VALU-bound. ----
__global__ __launch_bounds__(256) void k_gemm1(const float* __restrict__ x, const float* __restrict__ W1,
    const float* __restrict__ atts, const float* __restrict__ attd,
    __hip_bfloat16* __restrict__ h1b, float* __restrict__ as1, float* __restrict__ ad1){
  int tid = threadIdx.x;
  int n0 = blockIdx.x*8;
  int col = tid;
  const float4* w4 = (const float4*)(W1 + (size_t)col*INC);
  float acc[8];
  #pragma unroll
  for (int i = 0; i < 8; i++) acc[i] = 0.f;
  #pragma unroll 4
  for (int k4 = 0; k4 < INC/4; k4++){
    float4 wv = w4[k4];
    #pragma unroll
    for (int i = 0; i < 8; i++){
      // lane-independent address: compiler emits scalar (SGPR) load, no LDS, no VMEM per lane
      float4 xv = ((const float4*)(x + (size_t)(n0+i)*INC))[k4];
      acc[i] += wv.x*xv.x + wv.y*xv.y + wv.z*xv.z + wv.w*xv.w;
    }
  }
  float av_s = atts[col], av_d = attd[col];
  int head = tid >> 6;
  #pragma unroll
  for (int i = 0; i < 8; i++){
    h1b[((size_t)(n0+i))*HIDC + col] = __float2bfloat16(acc[i]);
    float ps = acc[i]*av_s, pd = acc[i]*av_d;
    #pragma unroll
    for (int off = 32; off > 0; off >>= 1){ ps += __shfl_down(ps, off); pd += __shfl_down(pd, off); }
    if ((tid & 63) == 0){ as1[(n0+i)*NH + head] = ps; ad1[(n0+i)*NH + head] = pd; }
  }
}

// ---- per-edge attention weights for layer1 ----
__global__ __launch_bounds__(256) void k_es(const int* __restrict__ src32, const int* __restrict__ dst32,
    const int* __restrict__ epos, const float* __restrict__ as1, const float* __restrict__ ad1,
    float4* __restrict__ es4){
  int e = blockIdx.x*256 + threadIdx.x;
  if (e >= NE) return;
  int s = src32[e], d = dst32[e];
  float4 vs = ((const float4*)as1)[s];
  float4 vd = ((const float4*)ad1)[d];
  float4 r;
  r.x = __expf(lrelu(vs.x + vd.x));
  r.y = __expf(lrelu(vs.y + vd.y));
  r.z = __expf(lrelu(vs.z + vd.z));
  r.w = __expf(lrelu(vs.w + vd.w));
  es4[epos[e]] = r;
}

// ---- layer1 aggregation: bf16 gather, precomputed es, 2 ch/thread, unroll-2 ----
__global__ __launch_bounds__(128) void k_agg1(const __hip_bfloat16* __restrict__ h1b,
    const float4* __restrict__ es4, const float* __restrict__ as1, const float* __restrict__ ad1,
    const int* __restrict__ rowptr, const int* __restrict__ colsrc,
    const float* __restrict__ b1, float* __restrict__ h1a){
  int n = blockIdx.x; int tid = threadIdx.x; int head = tid >> 5;
  const unsigned* h1u = (const unsigned*)h1b;

  float es_self = __expf(lrelu(as1[n*NH + head] + ad1[n*NH + head]));
  float den = 1e-16f + es_self;
  unsigned v = h1u[(size_t)n*(HIDC/2) + tid];
  float a0 = es_self * __uint_as_float(v << 16);
  float a1 = es_self * __uint_as_float(v & 0xffff0000u);

  int beg = rowptr[n], end = rowptr[n+1];
  int j = beg;
  for (; j + 1 < end; j += 2){
    int s0 = colsrc[j], s1 = colsrc[j+1];
    float4 e0 = es4[j], e1 = es4[j+1];
    unsigned v0 = h1u[(size_t)s0*(HIDC/2) + tid];
    unsigned v1 = h1u[(size_t)s1*(HIDC/2) + tid];
    float w0 = (head & 2) ? ((head & 1) ? e0.w : e0.z) : ((head & 1) ? e0.y : e0.x);
    float w1 = (head & 2) ? ((head & 1) ? e1.w : e1.z) : ((head & 1) ? e1.y : e1.x);
    den += w0 + w1;
    a0 += w0 * __uint_as_float(v0 << 16);
    a1 += w0 * __uint_as_float(v0 & 0xffff0000u);
    a0 += w1 * __uint_as_float(v1 << 16);
    a1 += w1 * __uint_as_float(v1 & 0xffff0000u);
  }
  if (j < end){
    int s0 = colsrc[j];
    float4 e0 = es4[j];
    unsigned v0 = h1u[(size_t)s0*(HIDC/2) + tid];
    float w0 = (head & 2) ? ((head & 1) ? e0.w : e0.z) : ((head & 1) ? e0.y : e0.x);
    den += w0;
    a0 += w0 * __uint_as_float(v0 << 16);
    a1 += w0 * __uint_as_float(v0 & 0xffff0000u);
  }

  float2 bb = ((const float2*)b1)[tid];
  float rinv = 1.f / den;
  float o0 = a0*rinv + bb.x;
  float o1 = a1*rinv + bb.y;
  o0 = o0 > 0.f ? o0 : (__expf(o0) - 1.f);
  o1 = o1 > 0.f ? o1 : (__expf(o1) - 1.f);
  ((float2*)(h1a + (size_t)n*HIDC))[tid] = make_float2(o0, o1);
}

// ---- layer2 GEMM: one node per thread, W2^T staged in LDS ----
__global__ __launch_bounds__(256) void k_gemm2(const float* __restrict__ h1a, const float* __restrict__ W2,
    const float* __restrict__ atts2, const float* __restrict__ attd2,
    float* __restrict__ h2, float* __restrict__ a2s, float* __restrict__ a2d){
  __shared__ float W2t[HIDC*OUTC];   // [k][c] transposed, 40 KB
  __shared__ float sA[OUTC], sD[OUTC];
  int tid = threadIdx.x;
  #pragma unroll
  for (int it = 0; it < (OUTC*HIDC)/256; it++){
    int idx = it*256 + tid;
    int c = idx >> 8, k = idx & 255;
    W2t[k*OUTC + c] = W2[idx];
  }
  if (tid < OUTC){ sA[tid] = atts2[tid]; sD[tid] = attd2[tid]; }
  __syncthreads();

  int n = blockIdx.x*256 + tid;
  if (n >= NN) return;

  float acc[OUTC];
  #pragma unroll
  for (int c = 0; c < OUTC; c++) acc[c] = 0.f;

  const float4* x4p = (const float4*)(h1a + (size_t)n*HIDC);
  const float4* w4p = (const float4*)W2t;
  #pragma unroll 2
  for (int k4 = 0; k4 < HIDC/4; k4++){
    float4 xv = x4p[k4];
    #pragma unroll
    for (int kk = 0; kk < 4; kk++){
      float xk = (kk==0) ? xv.x : (kk==1) ? xv.y : (kk==2) ? xv.z : xv.w;
      #pragma unroll
      for (int c4 = 0; c4 < OUTC/4; c4++){
        float4 wv = w4p[(k4*4 + kk)*(OUTC/4) + c4];
        acc[c4*4+0] += xk*wv.x;
        acc[c4*4+1] += xk*wv.y;
        acc[c4*4+2] += xk*wv.z;
        acc[c4*4+3] += xk*wv.w;
      }
    }
  }

  float s2 = 0.f, d2 = 0.f;
  #pragma unroll
  for (int c = 0; c < OUTC; c++){ s2 += acc[c]*sA[c]; d2 += acc[c]*sD[c]; }

  float* h2row = h2 + (size_t)n*OUTC;
  #pragma unroll
  for (int c4 = 0; c4 < OUTC/4; c4++){
    float4 v; v.x = acc[c4*4+0]; v.y = acc[c4*4+1]; v.z = acc[c4*4+2]; v.w = acc[c4*4+3];
    ((float4*)h2row)[c4] = v;
  }
  a2s[n] = s2; a2d[n] = d2;
}

// ---- layer2 aggregation: softmax-weighted mean + bias -> out ----
__global__ __launch_bounds__(64) void k_agg2(const float* __restrict__ h2, const float* __restrict__ a2s,
    const float* __restrict__ a2d, const int* __restrict__ rowptr, const int* __restrict__ colsrc,
    const float* __restrict__ b2, float* __restrict__ out){
  int n = blockIdx.x; int tid = threadIdx.x;
  float adn = a2d[n];
  float e = __expf(lrelu(a2s[n] + adn));
  float den = 1e-16f + e;
  float acc = (tid < OUTC) ? e * h2[(size_t)n*OUTC + tid] : 0.f;
  int beg = rowptr[n], end = rowptr[n+1];
  for (int j = beg; j < end; j++){
    int s = colsrc[j];
    float es = __expf(lrelu(a2s[s] + adn));
    if (tid < OUTC) acc += es * h2[(size_t)s*OUTC + tid];
    den += es;
  }
  if (tid < OUTC) out[(size_t)n*OUTC + tid] = acc/den + b2[tid];
}

extern "C" void kernel_launch(void* const* d_in, const int* in_sizes, int n_in,
                              void* d_out, int out_size, void* d_ws, size_t ws_size,
                              hipStream_t stream){
  const float* x    = (const float*)d_in[0];
  const void*  ei   = d_in[1];
  const float* W1   = (const float*)d_in[2];
  const float* as1w = (const float*)d_in[3];
  const float* ad1w = (const float*)d_in[4];
  const float* b1   = (const float*)d_in[5];
  const float* W2   = (const float*)d_in[6];
  const float* as2w = (const float*)d_in[7];
  const float* ad2w = (const float*)d_in[8];
  const float* b2   = (const float*)d_in[9];
  float* out = (float*)d_out;

  char* base = (char*)d_ws;
  size_t off = 0;
  auto alloc = [&](size_t bytes)->char*{ char* r = base + off; off += (bytes + 255) & ~(size_t)255; return r; };
  int* flag   = (int*)alloc(sizeof(int));
  int* src32  = (int*)alloc((size_t)NE*sizeof(int));
  int* dst32  = (int*)alloc((size_t)NE*sizeof(int));
  int* deg    = (int*)alloc((size_t)NN*sizeof(int));
  int* rowptr = (int*)alloc((size_t)(NN+1)*sizeof(int));
  int* fillc  = (int*)alloc((size_t)NN*sizeof(int));
  int* sums   = (int*)alloc(64*sizeof(int));
  int* colsrc = (int*)alloc((size_t)NE*sizeof(int));
  int* epos   = (int*)alloc((size_t)NE*sizeof(int));
  float4* es4 = (float4*)alloc((size_t)NE*sizeof(float4));
  __hip_bfloat16* h1b = (__hip_bfloat16*)alloc((size_t)NN*HIDC*sizeof(__hip_bfloat16));
  float* h1a  = (float*)alloc((size_t)NN*HIDC*sizeof(float));
  float* as1  = (float*)alloc((size_t)NN*NH*sizeof(float));
  float* ad1  = (float*)alloc((size_t)NN*NH*sizeof(float));
  float* h2   = (float*)alloc((size_t)NN*OUTC*sizeof(float));
  float* a2s  = (float*)alloc((size_t)NN*sizeof(float));
  float* a2d  = (float*)alloc((size_t)NN*sizeof(float));

  hipMemsetAsync(deg,   0, (size_t)NN*sizeof(int), stream);
  hipMemsetAsync(fillc, 0, (size_t)NN*sizeof(int), stream);

  int gE = (NE + 255)/256;
  int nchunks = (NN + 1023)/1024;
  k_detect<<<1, 64, 0, stream>>>((const long long*)ei, flag);
  k_convert<<<gE, 256, 0, stream>>>(ei, flag, src32, dst32);
  k_count<<<gE, 256, 0, stream>>>(dst32, deg);
  k_scan1<<<nchunks, 1024, 0, stream>>>(deg, rowptr, sums);
  k_scan2<<<1, 64, 0, stream>>>(sums, nchunks);
  k_scan3<<<(NN + 255)/256, 256, 0, stream>>>(rowptr, sums);
  k_fill<<<gE, 256, 0, stream>>>(src32, dst32, rowptr, fillc, colsrc, epos);
  k_gemm1<<<NN/8, 256, 0, stream>>>(x, W1, as1w, ad1w, h1b, as1, ad1);
  k_es<<<gE, 256, 0, stream>>>(src32, dst32, epos, as1, ad1, es4);
  k_agg1<<<NN, 128, 0, stream>>>(h1b, es4, as1, ad1, rowptr, colsrc, b1, h1a);
  k_gemm2<<<(NN + 255)/256, 256, 0, stream>>>(h1a, W2, as2w, ad2w, h2, a2s, a2d);
  k_agg2<<<NN, 64, 0, stream>>>(h2, a2s, a2d, rowptr, colsrc, b2, out);
}

// Round 6
// 357.139 us; speedup vs baseline: 1.7796x; 1.1258x over previous
//
#include <hip/hip_runtime.h>
#include <hip/hip_bf16.h>
#include <cstdint>
#include <cstddef>

#define NN 50000
#define NE 800000
#define INC 128
#define HIDC 256
#define NH 4
#define OUTC 40

typedef __attribute__((ext_vector_type(8))) short short8_t;
typedef __attribute__((ext_vector_type(4))) float f32x4_t;

__device__ __forceinline__ float lrelu(float x){ return x > 0.f ? x : 0.2f*x; }
__device__ __forceinline__ unsigned short bfr(float f){
  __hip_bfloat16 h = __float2bfloat16(f);
  return *reinterpret_cast<unsigned short*>(&h);
}

// ---- edge dtype detection: int64 view of int32 pairs gives values >= 2^32 ----
__global__ __launch_bounds__(64) void k_detect(const long long* __restrict__ ei, int* __restrict__ flag){
  int t = threadIdx.x;
  long long v = ei[(long long)t * (NE/64)];
  bool ok = (v >= 0) && (v < NN);
  unsigned long long m = __ballot(ok);
  if (t == 0) *flag = (m == 0xFFFFFFFFFFFFFFFFull) ? 1 : 0;
}

__global__ __launch_bounds__(256) void k_convert(const void* __restrict__ ei, const int* __restrict__ flag,
                                                 int* __restrict__ src32, int* __restrict__ dst32){
  int e = blockIdx.x*256 + threadIdx.x;
  if (e >= NE) return;
  int s, d;
  if (*flag){
    const long long* p = (const long long*)ei;
    s = (int)p[e]; d = (int)p[NE+e];
  } else {
    const int* p = (const int*)ei;
    s = p[e]; d = p[NE+e];
  }
  s = min(max(s,0),NN-1); d = min(max(d,0),NN-1);
  src32[e] = s; dst32[e] = d;
}

__global__ __launch_bounds__(256) void k_count(const int* __restrict__ dst32, int* __restrict__ deg){
  int e = blockIdx.x*256 + threadIdx.x;
  if (e < NE) atomicAdd(&deg[dst32[e]], 1);
}

// ---- exclusive scan of deg -> rowptr (3-kernel, chunk=1024) ----
__global__ __launch_bounds__(1024) void k_scan1(const int* __restrict__ deg, int* __restrict__ rowptr, int* __restrict__ sums){
  __shared__ int sh[1024];
  int t = threadIdx.x; int i = blockIdx.x*1024 + t;
  sh[t] = (i < NN) ? deg[i] : 0;
  __syncthreads();
  for (int off = 1; off < 1024; off <<= 1){
    int add = (t >= off) ? sh[t-off] : 0;
    __syncthreads();
    sh[t] += add;
    __syncthreads();
  }
  if (i < NN) rowptr[i+1] = sh[t];
  if (t == 1023) sums[blockIdx.x] = sh[1023];
}

__global__ void k_scan2(int* sums, int nchunks){
  if (threadIdx.x == 0 && blockIdx.x == 0){
    int acc = 0;
    for (int i = 0; i < nchunks; i++){ int v = sums[i]; sums[i] = acc; acc += v; }
  }
}

__global__ __launch_bounds__(256) void k_scan3(int* __restrict__ rowptr, const int* __restrict__ sums){
  int i = blockIdx.x*256 + threadIdx.x;
  if (i < NN) rowptr[i+1] += sums[i >> 10];
  if (i == 0) rowptr[0] = 0;
}

__global__ __launch_bounds__(256) void k_fill(const int* __restrict__ src32, const int* __restrict__ dst32,
                                              const int* __restrict__ rowptr, int* __restrict__ fill,
                                              int* __restrict__ colsrc, int* __restrict__ epos){
  int e = blockIdx.x*256 + threadIdx.x;
  if (e >= NE) return;
  int d = dst32[e];
  int pos = rowptr[d] + atomicAdd(&fill[d], 1);
  colsrc[pos] = src32[e];
  epos[e] = pos;
}

// ---- fp32 -> bf16 conversion (used for W1) ----
__global__ __launch_bounds__(256) void k_cvt(const float* __restrict__ in, unsigned short* __restrict__ out, int n4){
  int i = blockIdx.x*256 + threadIdx.x;
  if (i >= n4) return;
  float4 v = ((const float4*)in)[i];
  ushort4 o;
  o.x = bfr(v.x); o.y = bfr(v.y); o.z = bfr(v.z); o.w = bfr(v.w);
  ((ushort4*)out)[i] = o;
}

// ---- layer1 GEMM v4: MFMA bf16. Wave = 16 rows x 256 cols.
//      A frag: lane holds A[l&15][(l>>4)*8+j] (x converted in-kernel).
//      B frag: lane holds B[(l>>4)*8+j][l&15] = W1[l&15-th col row][8k contig] -> one b128 load.
//      C/D: col=l&15, row=(l>>4)*4+r (m89-verified). Attention dots fused in-register. ----
__global__ __launch_bounds__(256) void k_gemm1(const float* __restrict__ x, const unsigned short* __restrict__ w1b,
    const float* __restrict__ atts, const float* __restrict__ attd,
    unsigned short* __restrict__ h1b, float* __restrict__ as1, float* __restrict__ ad1){
  int tid = threadIdx.x;
  int wv = tid >> 6, l = tid & 63;
  int m0 = blockIdx.x*64 + wv*16;
  int lr = l & 15;   // A-row / B-col / D-col index
  int lk = l >> 4;   // k-block index

  // load + convert A fragments (4 k-tiles of 32)
  short8_t a[4];
  int arow = m0 + lr; if (arow > NN-1) arow = NN-1;
  const float* xrow = x + (size_t)arow*INC + lk*8;
  #pragma unroll
  for (int kt = 0; kt < 4; kt++){
    float4 f0 = *(const float4*)(xrow + kt*32);
    float4 f1 = *(const float4*)(xrow + kt*32 + 4);
    short8_t av;
    av[0] = (short)bfr(f0.x); av[1] = (short)bfr(f0.y);
    av[2] = (short)bfr(f0.z); av[3] = (short)bfr(f0.w);
    av[4] = (short)bfr(f1.x); av[5] = (short)bfr(f1.y);
    av[6] = (short)bfr(f1.z); av[7] = (short)bfr(f1.w);
    a[kt] = av;
  }

  const unsigned short* bbase = w1b + (size_t)lr*INC + lk*8;

  for (int h = 0; h < NH; h++){
    float ps[4] = {0.f,0.f,0.f,0.f};
    float pd[4] = {0.f,0.f,0.f,0.f};
    #pragma unroll
    for (int t = 0; t < 4; t++){
      int nt = h*4 + t;
      f32x4_t acc = {0.f,0.f,0.f,0.f};
      #pragma unroll
      for (int kt = 0; kt < 4; kt++){
        short8_t bv = *(const short8_t*)(bbase + (size_t)nt*16*INC + kt*32);
        acc = __builtin_amdgcn_mfma_f32_16x16x32_bf16(a[kt], bv, acc, 0, 0, 0);
      }
      float sa = atts[nt*16 + lr], sd = attd[nt*16 + lr];
      #pragma unroll
      for (int r = 0; r < 4; r++){
        float v = acc[r];
        ps[r] += v*sa; pd[r] += v*sd;
        int node = m0 + lk*4 + r;
        if (node < NN) h1b[(size_t)node*HIDC + nt*16 + lr] = bfr(v);
      }
    }
    // reduce ps/pd over the 16 lanes sharing a row (xor within 16-lane group)
    #pragma unroll
    for (int r = 0; r < 4; r++){
      float p = ps[r], q = pd[r];
      p += __shfl_xor(p, 1); p += __shfl_xor(p, 2); p += __shfl_xor(p, 4); p += __shfl_xor(p, 8);
      q += __shfl_xor(q, 1); q += __shfl_xor(q, 2); q += __shfl_xor(q, 4); q += __shfl_xor(q, 8);
      int node = m0 + lk*4 + r;
      if (lr == 0 && node < NN){ as1[node*NH + h] = p; ad1[node*NH + h] = q; }
    }
  }
}

// ---- per-edge attention weights for layer1 ----
__global__ __launch_bounds__(256) void k_es(const int* __restrict__ src32, const int* __restrict__ dst32,
    const int* __restrict__ epos, const float* __restrict__ as1, const float* __restrict__ ad1,
    float4* __restrict__ es4){
  int e = blockIdx.x*256 + threadIdx.x;
  if (e >= NE) return;
  int s = src32[e], d = dst32[e];
  float4 vs = ((const float4*)as1)[s];
  float4 vd = ((const float4*)ad1)[d];
  float4 r;
  r.x = __expf(lrelu(vs.x + vd.x));
  r.y = __expf(lrelu(vs.y + vd.y));
  r.z = __expf(lrelu(vs.z + vd.z));
  r.w = __expf(lrelu(vs.w + vd.w));
  es4[epos[e]] = r;
}

// ---- layer1 aggregation: bf16 gather, precomputed es, 2 ch/thread, unroll-2 ----
__global__ __launch_bounds__(128) void k_agg1(const __hip_bfloat16* __restrict__ h1b,
    const float4* __restrict__ es4, const float* __restrict__ as1, const float* __restrict__ ad1,
    const int* __restrict__ rowptr, const int* __restrict__ colsrc,
    const float* __restrict__ b1, float* __restrict__ h1a){
  int n = blockIdx.x; int tid = threadIdx.x; int head = tid >> 5;
  const unsigned* h1u = (const unsigned*)h1b;

  float es_self = __expf(lrelu(as1[n*NH + head] + ad1[n*NH + head]));
  float den = 1e-16f + es_self;
  unsigned v = h1u[(size_t)n*(HIDC/2) + tid];
  float a0 = es_self * __uint_as_float(v << 16);
  float a1 = es_self * __uint_as_float(v & 0xffff0000u);

  int beg = rowptr[n], end = rowptr[n+1];
  int j = beg;
  for (; j + 1 < end; j += 2){
    int s0 = colsrc[j], s1 = colsrc[j+1];
    float4 e0 = es4[j], e1 = es4[j+1];
    unsigned v0 = h1u[(size_t)s0*(HIDC/2) + tid];
    unsigned v1 = h1u[(size_t)s1*(HIDC/2) + tid];
    float w0 = (head & 2) ? ((head & 1) ? e0.w : e0.z) : ((head & 1) ? e0.y : e0.x);
    float w1 = (head & 2) ? ((head & 1) ? e1.w : e1.z) : ((head & 1) ? e1.y : e1.x);
    den += w0 + w1;
    a0 += w0 * __uint_as_float(v0 << 16);
    a1 += w0 * __uint_as_float(v0 & 0xffff0000u);
    a0 += w1 * __uint_as_float(v1 << 16);
    a1 += w1 * __uint_as_float(v1 & 0xffff0000u);
  }
  if (j < end){
    int s0 = colsrc[j];
    float4 e0 = es4[j];
    unsigned v0 = h1u[(size_t)s0*(HIDC/2) + tid];
    float w0 = (head & 2) ? ((head & 1) ? e0.w : e0.z) : ((head & 1) ? e0.y : e0.x);
    den += w0;
    a0 += w0 * __uint_as_float(v0 << 16);
    a1 += w0 * __uint_as_float(v0 & 0xffff0000u);
  }

  float2 bb = ((const float2*)b1)[tid];
  float rinv = 1.f / den;
  float o0 = a0*rinv + bb.x;
  float o1 = a1*rinv + bb.y;
  o0 = o0 > 0.f ? o0 : (__expf(o0) - 1.f);
  o1 = o1 > 0.f ? o1 : (__expf(o1) - 1.f);
  ((float2*)(h1a + (size_t)n*HIDC))[tid] = make_float2(o0, o1);
}

// ---- layer2 GEMM: one node per thread, W2^T staged in LDS ----
__global__ __launch_bounds__(256) void k_gemm2(const float* __restrict__ h1a, const float* __restrict__ W2,
    const float* __restrict__ atts2, const float* __restrict__ attd2,
    float* __restrict__ h2, float* __restrict__ a2s, float* __restrict__ a2d){
  __shared__ float W2t[HIDC*OUTC];   // [k][c] transposed, 40 KB
  __shared__ float sA[OUTC], sD[OUTC];
  int tid = threadIdx.x;
  #pragma unroll
  for (int it = 0; it < (OUTC*HIDC)/256; it++){
    int idx = it*256 + tid;
    int c = idx >> 8, k = idx & 255;
    W2t[k*OUTC + c] = W2[idx];
  }
  if (tid < OUTC){ sA[tid] = atts2[tid]; sD[tid] = attd2[tid]; }
  __syncthreads();

  int n = blockIdx.x*256 + tid;
  if (n >= NN) return;

  float acc[OUTC];
  #pragma unroll
  for (int c = 0; c < OUTC; c++) acc[c] = 0.f;

  const float4* x4p = (const float4*)(h1a + (size_t)n*HIDC);
  const float4* w4p = (const float4*)W2t;
  #pragma unroll 2
  for (int k4 = 0; k4 < HIDC/4; k4++){
    float4 xv = x4p[k4];
    #pragma unroll
    for (int kk = 0; kk < 4; kk++){
      float xk = (kk==0) ? xv.x : (kk==1) ? xv.y : (kk==2) ? xv.z : xv.w;
      #pragma unroll
      for (int c4 = 0; c4 < OUTC/4; c4++){
        float4 wv = w4p[(k4*4 + kk)*(OUTC/4) + c4];
        acc[c4*4+0] += xk*wv.x;
        acc[c4*4+1] += xk*wv.y;
        acc[c4*4+2] += xk*wv.z;
        acc[c4*4+3] += xk*wv.w;
      }
    }
  }

  float s2 = 0.f, d2 = 0.f;
  #pragma unroll
  for (int c = 0; c < OUTC; c++){ s2 += acc[c]*sA[c]; d2 += acc[c]*sD[c]; }

  float* h2row = h2 + (size_t)n*OUTC;
  #pragma unroll
  for (int c4 = 0; c4 < OUTC/4; c4++){
    float4 v; v.x = acc[c4*4+0]; v.y = acc[c4*4+1]; v.z = acc[c4*4+2]; v.w = acc[c4*4+3];
    ((float4*)h2row)[c4] = v;
  }
  a2s[n] = s2; a2d[n] = d2;
}

// ---- layer2 aggregation: softmax-weighted mean + bias -> out ----
__global__ __launch_bounds__(64) void k_agg2(const float* __restrict__ h2, const float* __restrict__ a2s,
    const float* __restrict__ a2d, const int* __restrict__ rowptr, const int* __restrict__ colsrc,
    const float* __restrict__ b2, float* __restrict__ out){
  int n = blockIdx.x; int tid = threadIdx.x;
  float adn = a2d[n];
  float e = __expf(lrelu(a2s[n] + adn));
  float den = 1e-16f + e;
  float acc = (tid < OUTC) ? e * h2[(size_t)n*OUTC + tid] : 0.f;
  int beg = rowptr[n], end = rowptr[n+1];
  for (int j = beg; j < end; j++){
    int s = colsrc[j];
    float es = __expf(lrelu(a2s[s] + adn));
    if (tid < OUTC) acc += es * h2[(size_t)s*OUTC + tid];
    den += es;
  }
  if (tid < OUTC) out[(size_t)n*OUTC + tid] = acc/den + b2[tid];
}

extern "C" void kernel_launch(void* const* d_in, const int* in_sizes, int n_in,
                              void* d_out, int out_size, void* d_ws, size_t ws_size,
                              hipStream_t stream){
  const float* x    = (const float*)d_in[0];
  const void*  ei   = d_in[1];
  const float* W1   = (const float*)d_in[2];
  const float* as1w = (const float*)d_in[3];
  const float* ad1w = (const float*)d_in[4];
  const float* b1   = (const float*)d_in[5];
  const float* W2   = (const float*)d_in[6];
  const float* as2w = (const float*)d_in[7];
  const float* ad2w = (const float*)d_in[8];
  const float* b2   = (const float*)d_in[9];
  float* out = (float*)d_out;

  char* base = (char*)d_ws;
  size_t off = 0;
  auto alloc = [&](size_t bytes)->char*{ char* r = base + off; off += (bytes + 255) & ~(size_t)255; return r; };
  int* flag   = (int*)alloc(sizeof(int));
  int* src32  = (int*)alloc((size_t)NE*sizeof(int));
  int* dst32  = (int*)alloc((size_t)NE*sizeof(int));
  int* deg    = (int*)alloc((size_t)NN*sizeof(int));
  int* rowptr = (int*)alloc((size_t)(NN+1)*sizeof(int));
  int* fillc  = (int*)alloc((size_t)NN*sizeof(int));
  int* sums   = (int*)alloc(64*sizeof(int));
  int* colsrc = (int*)alloc((size_t)NE*sizeof(int));
  int* epos   = (int*)alloc((size_t)NE*sizeof(int));
  float4* es4 = (float4*)alloc((size_t)NE*sizeof(float4));
  unsigned short* w1b = (unsigned short*)alloc((size_t)HIDC*INC*sizeof(unsigned short));
  unsigned short* h1b = (unsigned short*)alloc((size_t)NN*HIDC*sizeof(unsigned short));
  float* h1a  = (float*)alloc((size_t)NN*HIDC*sizeof(float));
  float* as1  = (float*)alloc((size_t)NN*NH*sizeof(float));
  float* ad1  = (float*)alloc((size_t)NN*NH*sizeof(float));
  float* h2   = (float*)alloc((size_t)NN*OUTC*sizeof(float));
  float* a2s  = (float*)alloc((size_t)NN*sizeof(float));
  float* a2d  = (float*)alloc((size_t)NN*sizeof(float));

  hipMemsetAsync(deg,   0, (size_t)NN*sizeof(int), stream);
  hipMemsetAsync(fillc, 0, (size_t)NN*sizeof(int), stream);

  int gE = (NE + 255)/256;
  int nchunks = (NN + 1023)/1024;
  k_detect<<<1, 64, 0, stream>>>((const long long*)ei, flag);
  k_convert<<<gE, 256, 0, stream>>>(ei, flag, src32, dst32);
  k_count<<<gE, 256, 0, stream>>>(dst32, deg);
  k_scan1<<<nchunks, 1024, 0, stream>>>(deg, rowptr, sums);
  k_scan2<<<1, 64, 0, stream>>>(sums, nchunks);
  k_scan3<<<(NN + 255)/256, 256, 0, stream>>>(rowptr, sums);
  k_fill<<<gE, 256, 0, stream>>>(src32, dst32, rowptr, fillc, colsrc, epos);
  k_cvt<<<(HIDC*INC/4 + 255)/256, 256, 0, stream>>>(W1, w1b, HIDC*INC/4);
  k_gemm1<<<(NN + 63)/64, 256, 0, stream>>>(x, w1b, as1w, ad1w, h1b, as1, ad1);
  k_es<<<gE, 256, 0, stream>>>(src32, dst32, epos, as1, ad1, es4);
  k_agg1<<<NN, 128, 0, stream>>>((const __hip_bfloat16*)h1b, es4, as1, ad1, rowptr, colsrc, b1, h1a);
  k_gemm2<<<(NN + 255)/256, 256, 0, stream>>>(h1a, W2, as2w, ad2w, h2, a2s, a2d);
  k_agg2<<<NN, 64, 0, stream>>>(h2, a2s, a2d, rowptr, colsrc, b2, out);
}